// Round 2
// baseline (149.706 us; speedup 1.0000x reference)
//
#include <hip/hip_runtime.h>
#include <stdint.h>

typedef unsigned int u32;
typedef unsigned long long u64;

#define HW      3136     // 56*56

// d_ws layout (ab workspace eliminated; only weight products remain)
#define WB_OFF   0        // 4608 u32  (18432 B)  packed weights
#define BF_OFF   18432    // 9*128 f32 (4608 B)   per-(class,o) base, alpha-folded
#define N2A_OFF  23040    // 128 f32   (512 B)    -2*alpha

// ---------------------------------------------------------------------------
// Weight synthesis kernel: one block per output channel o.
// sign(w) = sign(m + rv.z) (rsqrt normalizer is positive), packed 128 ch ->
// 4 u32 words per tap; Bf = alpha-folded base + border-correction table;
// n2a = -2*alpha.  (Unchanged, proven code; grid shrunk to 128 blocks.)
__global__ __launch_bounds__(256) void k_wsyn(
    const float* __restrict__ Alpha, const float* __restrict__ M,
    const float* __restrict__ Z, const float* __restrict__ rv,
    char* __restrict__ ws)
{
  int t = threadIdx.x;
  u32*   wb  = (u32*)(ws + WB_OFF);
  float* Bf  = (float*)(ws + BF_OFF);
  float* n2a = (float*)(ws + N2A_OFF);
  __shared__ float sw[1152];
  __shared__ u32 sbits[36];
  __shared__ int spc[9];
  int o = blockIdx.x;
  float r0 = rv[0], r1 = rv[1], r2 = rv[2], r3 = rv[3], r4 = rv[4];
  const float4* M4 = (const float4*)M;
  const float4* Z4 = (const float4*)Z;
  float4* sw4 = (float4*)sw;

  for (int j = t; j < 288; j += 256) {
    float4 a = M4[o * 288 + j];
    float4 z;
    z = Z4[0 * 36864 + o * 288 + j];
    a.x = fmaf(r0, z.x, a.x); a.y = fmaf(r0, z.y, a.y);
    a.z = fmaf(r0, z.z, a.z); a.w = fmaf(r0, z.w, a.w);
    z = Z4[1 * 36864 + o * 288 + j];
    a.x = fmaf(r1, z.x, a.x); a.y = fmaf(r1, z.y, a.y);
    a.z = fmaf(r1, z.z, a.z); a.w = fmaf(r1, z.w, a.w);
    z = Z4[2 * 36864 + o * 288 + j];
    a.x = fmaf(r2, z.x, a.x); a.y = fmaf(r2, z.y, a.y);
    a.z = fmaf(r2, z.z, a.z); a.w = fmaf(r2, z.w, a.w);
    z = Z4[3 * 36864 + o * 288 + j];
    a.x = fmaf(r3, z.x, a.x); a.y = fmaf(r3, z.y, a.y);
    a.z = fmaf(r3, z.z, a.z); a.w = fmaf(r3, z.w, a.w);
    z = Z4[4 * 36864 + o * 288 + j];
    a.x = fmaf(r4, z.x, a.x); a.y = fmaf(r4, z.y, a.y);
    a.z = fmaf(r4, z.z, a.z); a.w = fmaf(r4, z.w, a.w);
    sw4[j] = a;
  }
  __syncthreads();

  if (t < 36) {                       // t = tap*4 + word
    int tap = t >> 2;
    int wd  = t & 3;
    u32 bits = 0;
#pragma unroll
    for (int c = 0; c < 32; ++c) {
      float v = sw[(wd * 32 + c) * 9 + tap];
      bits |= (v > 0.0f ? 1u : 0u) << c;
    }
    wb[(o * 9 + tap) * 4 + wd] = bits;
    sbits[t] = bits;
  }
  __syncthreads();
  if (t < 9)
    spc[t] = __popc(sbits[4 * t]) + __popc(sbits[4 * t + 1])
           + __popc(sbits[4 * t + 2]) + __popc(sbits[4 * t + 3]);
  __syncthreads();
  if (t < 9) {                        // t = edge class ht*3+wt
    int ht = t / 3, wt = t - ht * 3;
    int corr = 0;
#pragma unroll
    for (int tap = 0; tap < 9; ++tap) {
      int dh = tap / 3, dw = tap - dh * 3;
      int inv = ((ht == 0) & (dh == 0)) | ((ht == 2) & (dh == 2)) |
                ((wt == 0) & (dw == 0)) | ((wt == 2) & (dw == 2));
      if (inv) corr += 128 - 2 * spc[tap];
    }
    Bf[t * 128 + o] = (float)(1152 - corr) * Alpha[o];
  }
  if (t == 0) n2a[o] = -2.0f * Alpha[o];
}

// ---------------------------------------------------------------------------
// Conv with in-block activation packing: block = (image b, 4-row band).
// Packs 6 input rows (4 + halo) x 58 padded cols of sign bits into LDS
// directly from x (zero borders -> the Bf correction tables apply
// unchanged), then computes 4x56 px x 128 o.  Removes the ab global
// round-trip and the 421 apack/ring blocks of the old prep kernel.
//
// Thread task = (quad qd 0..55, o-group og 0..7 of 16 o); og varies
// fastest so the 8 lanes of a group share one qd -> A-tile LDS reads are
// same-address broadcasts.  Weight slots are skewed by (o>>4) so the 8
// og-groups of a wave hit 8 distinct bank-quads (uint4-granular padding
// cannot achieve this: 16*(4k) = 0 mod 32).  No __launch_bounds__ cap:
// the 72-reg A-tile must stay in VGPRs (round-1 lesson: a 64-VGPR cap
// made the compiler re-fetch the tile per oi -> 690 MB FETCH).
__global__ __launch_bounds__(256) void k_conv2(
    const float* __restrict__ x, const char* __restrict__ ws,
    float* __restrict__ out)
{
  __shared__ uint4 sab[6 * 58];      // padded sign-bit tile, 5568 B
  __shared__ uint4 swb[1160];        // o*9 + (o>>4) + tap, 18560 B
  __shared__ float sBfX[9 * 136];    // class*136 + o + (o>>4)
  __shared__ float sn2aX[136];       // o + (o>>4)

  const uint4* wbg  = (const uint4*)(ws + WB_OFF);
  const float* BfG  = (const float*)(ws + BF_OFF);
  const float* n2aG = (const float*)(ws + N2A_OFF);

  int t    = threadIdx.x;
  int blk  = blockIdx.x;             // 0..447
  int b    = blk / 14;
  int band = blk - b * 14;
  int h0   = band * 4;

  // ---- stage weights / tables, zero the activation tile ----
  for (int j = t; j < 1152; j += 256) {
    int o = j / 9, tap = j - o * 9;
    swb[o * 9 + (o >> 4) + tap] = wbg[j];
    int cl = j >> 7, oo = j & 127;
    sBfX[cl * 136 + oo + (oo >> 4)] = BfG[j];
  }
  if (t < 128) sn2aX[t + (t >> 4)] = n2aG[t];
  {
    u32* sz = (u32*)sab;
    for (int j = t; j < 6 * 58 * 4; j += 256) sz[j] = 0;
  }
  __syncthreads();

  // ---- pack: item = (row 0..5, quad 0..13, word g 0..3) ----
  u32* sabw = (u32*)sab;
  for (int i = t; i < 336; i += 256) {
    int g    = i & 3;
    int rq   = i >> 2;
    int row  = rq / 14;
    int quad = rq - row * 14;
    int in_row = h0 - 1 + row;
    if (in_row >= 0 && in_row < 56) {
      const float4* X4 = (const float4*)x
          + ((size_t)(b * 128 + g * 32)) * (HW / 4) + in_row * 14 + quad;
      u32 m0 = 0, m1 = 0, m2 = 0, m3 = 0;
#pragma unroll 8
      for (int c = 0; c < 32; ++c) {
        float4 f = X4[(size_t)c * (HW / 4)];
        m0 |= (f.x > 0.0f ? 1u : 0u) << c;
        m1 |= (f.y > 0.0f ? 1u : 0u) << c;
        m2 |= (f.z > 0.0f ? 1u : 0u) << c;
        m3 |= (f.w > 0.0f ? 1u : 0u) << c;
      }
      int colb = (row * 58 + 1 + quad * 4) * 4 + g;   // u32 index
      sabw[colb]      = m0;
      sabw[colb + 4]  = m1;
      sabw[colb + 8]  = m2;
      sabw[colb + 12] = m3;
    }
  }
  __syncthreads();

  // ---- conv: tasks (qd, og), 448 per block, 2 rounds/thread ----
  for (int task = t; task < 448; task += 256) {
    int og = task & 7;
    int qd = task >> 3;
    int r  = qd / 14;
    int w4 = qd - r * 14;
    int w0 = w4 * 4;
    int h  = h0 + r;
    int o0 = og * 16;

    u32 A[3][6][4];
#pragma unroll
    for (int rr = 0; rr < 3; ++rr)
#pragma unroll
      for (int cc = 0; cc < 6; ++cc) {
        uint4 v = sab[(r + rr) * 58 + w0 + cc];
        A[rr][cc][0] = v.x; A[rr][cc][1] = v.y;
        A[rr][cc][2] = v.z; A[rr][cc][3] = v.w;
      }

    int ht  = (h == 0) ? 0 : (h == 55 ? 6 : 3);
    int cl0 = ht + ((w0 == 0) ? 0 : 1);
    int cl1 = ht + 1;
    int cl3 = ht + ((w0 == 52) ? 2 : 1);

    const uint4* wp   = &swb[o0 * 9 + og];       // wp[oi*9 + tap]
    int          oX   = o0 + og;                  // skewed o index base
    float*       outp = out + ((size_t)(b * 128 + o0)) * HW + h * 56 + w0;

#pragma unroll 4
    for (int oi = 0; oi < 16; ++oi) {
      int s0 = 0, s1 = 0, s2 = 0, s3 = 0;
#pragma unroll
      for (int dh = 0; dh < 3; ++dh)
#pragma unroll
        for (int dw = 0; dw < 3; ++dw) {
          uint4 wv = wp[oi * 9 + dh * 3 + dw];
#pragma unroll
          for (int k = 0; k < 4; ++k) {
            u32 wk = (&wv.x)[k];
            s0 += __popc(A[dh][dw + 0][k] ^ wk);
            s1 += __popc(A[dh][dw + 1][k] ^ wk);
            s2 += __popc(A[dh][dw + 2][k] ^ wk);
            s3 += __popc(A[dh][dw + 3][k] ^ wk);
          }
        }
      float na = sn2aX[oX + oi];
      float4 ov;
      ov.x = fmaf((float)s0, na, sBfX[cl0 * 136 + oX + oi]);
      ov.y = fmaf((float)s1, na, sBfX[cl1 * 136 + oX + oi]);
      ov.z = fmaf((float)s2, na, sBfX[cl1 * 136 + oX + oi]);
      ov.w = fmaf((float)s3, na, sBfX[cl3 * 136 + oX + oi]);
      *(float4*)(outp + (size_t)oi * HW) = ov;
    }
  }
}

// ---------------------------------------------------------------------------
extern "C" void kernel_launch(void* const* d_in, const int* in_sizes, int n_in,
                              void* d_out, int out_size, void* d_ws, size_t ws_size,
                              hipStream_t stream)
{
  const float* x     = (const float*)d_in[0];
  const float* Alpha = (const float*)d_in[1];
  const float* M     = (const float*)d_in[2];
  const float* Z     = (const float*)d_in[3];
  const float* rv    = (const float*)d_in[4];
  float* out         = (float*)d_out;
  char*  ws          = (char*)d_ws;

  k_wsyn<<<128, 256, 0, stream>>>(Alpha, M, Z, rv, ws);
  k_conv2<<<448, 256, 0, stream>>>(x, ws, out);
}